// Round 10
// baseline (198.531 us; speedup 1.0000x reference)
//
#include <hip/hip_runtime.h>
#include <hip/hip_bf16.h>

// out[m, f] = sum_e cos(x[m, e] + theta[e & 7]) * W[f, e]
// M = 65536, N = K = 512.  bf16 MFMA GEMM, A = cos(x+theta) fused.
//
// PERSISTENT blocks, grid=256 (1/CU), 8 stripes of BM=32 rows each.
// x staged with global_load_lds (fp32, linear 64 KB buffer F, zero VGPR cost)
// issued at kf=0 of the current stripe's K-loop; cos+bf16 pack (v_cos +
// v_cvt_pk_bf16_f32) runs at kf=12/14 into the double-buffered swizzled bf16
// tile T[2] (2 x 32 KB).  vmcnt(8) hand-count: at kf12 the only newer vmem
// ops are B(13),B(14) = 8 loads -> all older glds retired (in-order).
// Each wave's F region is written and read only by itself -> no mid-loop
// barrier; ONE barrier per stripe (T visibility).  B: fragment-major bf16 W
// in d_ws, 2-ahead 3-buffer.  Stores fire-and-forget, drain under next loop.
// LDS 128 KB -> 1 block/CU; regs ~130 incl. AGPR under (512,2) cap: NO SPILL.

typedef __attribute__((ext_vector_type(8))) short short8;   // 8 x bf16
typedef __attribute__((ext_vector_type(4))) float f32x4;    // MFMA acc frag

static constexpr int KD  = 512;
static constexpr int ND  = 512;
static constexpr int BM  = 32;
static constexpr int NKF = 16;           // K steps of 32
static constexpr int MPB = 256;          // rows per persistent block
static constexpr int NST = MPB / BM;     // 8 stripes

static __device__ __forceinline__ unsigned short f2bf(float f) {
    unsigned int b = __builtin_bit_cast(unsigned int, f);
    b += 0x7FFFu + ((b >> 16) & 1u);
    return (unsigned short)(b >> 16);
}

// cos(2*pi*rev) via v_cos_f32 (input in revolutions, fract range-reduce)
static __device__ __forceinline__ float fast_cos_rev(float rev) {
    float r = __builtin_amdgcn_fractf(rev);
    float c;
    asm("v_cos_f32 %0, %1" : "=v"(c) : "v"(r));
    return c;
}

// Pack W into MFMA-fragment-major bf16:
//   WbF[((n_blk*16 + kf)*64 + lane)*8 + j] =
//       bf16( W[n_blk*16 + (lane&15)][kf*32 + (lane>>4)*8 + j] )
__global__ void cvt_w_frag(const float* __restrict__ W,
                           unsigned short* __restrict__ WbF) {
    const int i    = blockIdx.x * 256 + threadIdx.x;  // 0..32767 fragments
    const int lane = i & 63;
    const int kf   = (i >> 6) & 15;
    const int nblk = i >> 10;                         // 0..31
    const int row  = nblk * 16 + (lane & 15);         // f index
    const int col  = kf * 32 + (lane >> 4) * 8;       // e index
    const float* p = W + (size_t)row * KD + col;
    float4 w0 = *reinterpret_cast<const float4*>(p);
    float4 w1 = *reinterpret_cast<const float4*>(p + 4);
    short8 t8;
    t8[0] = (short)f2bf(w0.x); t8[1] = (short)f2bf(w0.y);
    t8[2] = (short)f2bf(w0.z); t8[3] = (short)f2bf(w0.w);
    t8[4] = (short)f2bf(w1.x); t8[5] = (short)f2bf(w1.y);
    t8[6] = (short)f2bf(w1.z); t8[7] = (short)f2bf(w1.w);
    *reinterpret_cast<short8*>(WbF + (size_t)i * 8) = t8;
}

template <bool PRECVT>
__global__ __launch_bounds__(512, 2)
void fused_qgemm(const float* __restrict__ x, const float* __restrict__ theta,
                 const float* __restrict__ W, const unsigned short* __restrict__ WbF,
                 float* __restrict__ out) {
    __shared__ float          F[BM * KD];        // 64 KB fp32 staging, linear
    __shared__ unsigned short T[2][BM * KD];     // 2 x 32 KB bf16, swizzled

    const int tid  = threadIdx.x;
    const int lane = tid & 63;
    const int wave = tid >> 6;                   // 0..7
    const int mb   = blockIdx.x * MPB;

    const int frow = lane & 15;
    const int fkg  = lane >> 4;

    constexpr float INV2PI = 0.15915493667125702f;
    float thC[8];
#pragma unroll
    for (int j = 0; j < 8; ++j) thC[j] = theta[j] * INV2PI;

    // ---- glds mapping: round r, thread t -> x[mb+s*32 + r*4 + (t>>7)][(t&127)*4 ..+3]
    //      F byte off = r*8192 + t*16  (wave-uniform base + lane*16)
    const int grow = tid >> 7;                   // 0..3
    const int gcol = (tid & 127) * 4;
    const float* xbase = x + (size_t)(mb + grow) * KD + gcol;

    auto issueX = [&](int s) {
#pragma unroll
        for (int r = 0; r < 8; ++r) {
            const float* gp = xbase + (size_t)(s * BM + r * 4) * KD;
            __builtin_amdgcn_global_load_lds(
                (const __attribute__((address_space(1))) void*)gp,
                (__attribute__((address_space(3))) void*)&F[r * 2048 + wave * 256],
                16, 0, 0);
        }
    };

    // pack round r: thread t converts the 4 floats it loaded in round r
    const int tbase = (tid & 1) * 4;             // theta index base: gcol & 7
    auto packX = [&](int r, unsigned short* Tb) {
        float4 v = *reinterpret_cast<const float4*>(&F[r * 2048 + tid * 4]);
        const int row = r * 4 + grow;
        float c0 = fast_cos_rev(__builtin_fmaf(v.x, INV2PI, thC[tbase + 0]));
        float c1 = fast_cos_rev(__builtin_fmaf(v.y, INV2PI, thC[tbase + 1]));
        float c2 = fast_cos_rev(__builtin_fmaf(v.z, INV2PI, thC[tbase + 2]));
        float c3 = fast_cos_rev(__builtin_fmaf(v.w, INV2PI, thC[tbase + 3]));
        unsigned int p01, p23;
        asm("v_cvt_pk_bf16_f32 %0, %1, %2" : "=v"(p01) : "v"(c0), "v"(c1));
        asm("v_cvt_pk_bf16_f32 %0, %1, %2" : "=v"(p23) : "v"(c2), "v"(c3));
        const int byte = row * 1024 + ((gcol * 2) ^ ((row & 7) << 4));
        uint2 pk; pk.x = p01; pk.y = p23;
        *reinterpret_cast<uint2*>(reinterpret_cast<char*>(Tb) + byte) = pk;
    };

    // ---- B: fragment-major base (fully coalesced 16B/lane loads) ----
    const unsigned short* wbase =
        PRECVT ? (WbF + ((size_t)wave * 4096 + lane) * 8) : nullptr;
    const float* wpf[4];
#pragma unroll
    for (int jn = 0; jn < 4; ++jn)
        wpf[jn] = W + (size_t)(wave * 64 + jn * 16 + frow) * KD + fkg * 8;

    auto loadB = [&](int kf, short8* dst) {
#pragma unroll
        for (int jn = 0; jn < 4; ++jn) {
            if (PRECVT) {
                dst[jn] = *reinterpret_cast<const short8*>(
                    wbase + (size_t)(jn * 16 + kf) * 512);
            } else {
                float4 w0 = *reinterpret_cast<const float4*>(wpf[jn] + kf * 32);
                float4 w1 = *reinterpret_cast<const float4*>(wpf[jn] + kf * 32 + 4);
                short8 t8;
                t8[0] = (short)f2bf(w0.x); t8[1] = (short)f2bf(w0.y);
                t8[2] = (short)f2bf(w0.z); t8[3] = (short)f2bf(w0.w);
                t8[4] = (short)f2bf(w1.x); t8[5] = (short)f2bf(w1.y);
                t8[6] = (short)f2bf(w1.z); t8[7] = (short)f2bf(w1.w);
                dst[jn] = t8;
            }
        }
    };

    auto loadA = [&](const unsigned short* buf, int kf, short8* dst) {
#pragma unroll
        for (int i = 0; i < 2; ++i) {
            const int row  = i * 16 + frow;
            const int byte = row * 1024 + (((kf * 32 + fkg * 8) * 2) ^ ((row & 7) << 4));
            dst[i] = *reinterpret_cast<const short8*>(
                reinterpret_cast<const char*>(buf) + byte);
        }
    };

    short8 bb[3][4];
    short8 aa[2][2];
    f32x4  acc[2][4];
#pragma unroll
    for (int i = 0; i < 2; ++i)
#pragma unroll
        for (int j = 0; j < 4; ++j) acc[i][j] = (f32x4)(0.0f);

    // ---- prologue: glds stripe 0, then B(0),B(1); wait; pack; barrier ----
    issueX(0);
    loadB(0, bb[0]);
    loadB(1, bb[1]);
    asm volatile("s_waitcnt vmcnt(8)" ::: "memory");   // 8 B-loads newer than glds
    __builtin_amdgcn_sched_barrier(0);
#pragma unroll
    for (int r = 0; r < 8; ++r) packX(r, (unsigned short*)T[0]);
    __syncthreads();

    for (int s = 0; s < NST; ++s) {
        const unsigned short* curT = T[s & 1];
        unsigned short*       nxtT = (unsigned short*)T[(s & 1) ^ 1];
        const bool more = (s + 1 < NST);

        loadA(curT, 0, aa[0]);
#pragma unroll
        for (int kf = 0; kf < NKF; ++kf) {
            if (kf == 0 && more) issueX(s + 1);
            if (kf + 1 < NKF) loadA(curT, kf + 1, aa[(kf + 1) & 1]);
            if (kf + 2 < NKF) loadB(kf + 2, bb[(kf + 2) % 3]);
            if (more && kf == 12) {
                // newest outstanding vmem = B(13),B(14) = 8 loads -> glds done
                asm volatile("s_waitcnt vmcnt(8)" ::: "memory");
                __builtin_amdgcn_sched_barrier(0);
                packX(0, nxtT); packX(1, nxtT); packX(2, nxtT); packX(3, nxtT);
            }
            if (more && kf == 14) {
                packX(4, nxtT); packX(5, nxtT); packX(6, nxtT); packX(7, nxtT);
            }
            __builtin_amdgcn_sched_barrier(0);
#pragma unroll
            for (int i = 0; i < 2; ++i)
#pragma unroll
                for (int jn = 0; jn < 4; ++jn)
                    acc[i][jn] = __builtin_amdgcn_mfma_f32_16x16x32_bf16(
                        bb[kf % 3][jn], aa[kf & 1][i], acc[i][jn], 0, 0, 0);
        }

        // ---- store stripe s (fire-and-forget; drains under next K-loop) ----
        float* op = out + (size_t)(mb + s * BM + frow) * ND + wave * 64 + fkg * 4;
#pragma unroll
        for (int i = 0; i < 2; ++i)
#pragma unroll
            for (int jn = 0; jn < 4; ++jn) {
                *reinterpret_cast<f32x4*>(op + (size_t)(i * 16) * ND + jn * 16) =
                    acc[i][jn];
                acc[i][jn] = (f32x4)(0.0f);
            }
        if (more) { loadB(0, bb[0]); loadB(1, bb[1]); }  // next stripe kf=0,1
        __syncthreads();
    }
}

extern "C" void kernel_launch(void* const* d_in, const int* in_sizes, int n_in,
                              void* d_out, int out_size, void* d_ws, size_t ws_size,
                              hipStream_t stream) {
    const float* x     = (const float*)d_in[0];
    const float* theta = (const float*)d_in[1];
    const float* W     = (const float*)d_in[2];
    float* out         = (float*)d_out;

    const int M      = in_sizes[0] / KD;       // 65536
    const int wElems = in_sizes[2];            // 512*512

    if (ws_size >= (size_t)wElems * sizeof(unsigned short)) {
        unsigned short* WbF = (unsigned short*)d_ws;
        cvt_w_frag<<<wElems / 8 / 256, 256, 0, stream>>>(W, WbF);
        fused_qgemm<true><<<M / MPB, 512, 0, stream>>>(x, theta, W, WbF, out);
    } else {
        fused_qgemm<false><<<M / MPB, 512, 0, stream>>>(x, theta, W, nullptr, out);
    }
}

// Round 11
// 194.885 us; speedup vs baseline: 1.0187x; 1.0187x over previous
//
#include <hip/hip_runtime.h>
#include <hip/hip_bf16.h>

// out[m, f] = sum_e cos(x[m, e] + theta[e & 7]) * W[f, e]
// M = 65536, N = K = 512.  bf16 MFMA GEMM, A = cos(x+theta) fused.
//
// Grid = 256 (1 block/CU), each block owns 256 rows = 8 stripes of BM=32.
// Overlap WITHOUT register cost / inline waits:
//   - stripe s's K-loop issues global_load_lds (raw fp32 x -> F, 64 KB,
//     zero VGPRs) for stripe s+1 at kf=0; HBM latency+BW hides under K-loop.
//   - __syncthreads() after the K-loop: compiler emits vmcnt(0) before
//     s_barrier -> glds completion is correct by construction.
//   - pack F -> A[next] (fract + v_cos + v_cvt_pk_bf16_f32) between barriers.
//   - out-stores fire-and-forget, drain under next stripe's K-loop.
// K-loop = round-5's proven spill-free loop (fragment-major B 2-ahead,
// A ds_read 1-ahead, sched_barrier(0)-pinned).  LDS = 2x32 KB A + 64 KB F.

typedef __attribute__((ext_vector_type(8))) short short8;   // 8 x bf16
typedef __attribute__((ext_vector_type(4))) float f32x4;    // MFMA acc frag

static constexpr int KD  = 512;
static constexpr int ND  = 512;
static constexpr int BM  = 32;
static constexpr int NKF = 16;           // K steps of 32
static constexpr int MPB = 256;          // rows per block
static constexpr int NST = MPB / BM;     // 8 stripes

static __device__ __forceinline__ unsigned short f2bf(float f) {
    unsigned int b = __builtin_bit_cast(unsigned int, f);
    b += 0x7FFFu + ((b >> 16) & 1u);
    return (unsigned short)(b >> 16);
}

// cos(2*pi*rev) via v_cos_f32 (input in revolutions, fract range-reduce)
static __device__ __forceinline__ float fast_cos_rev(float rev) {
    float r = __builtin_amdgcn_fractf(rev);
    float c;
    asm("v_cos_f32 %0, %1" : "=v"(c) : "v"(r));
    return c;
}

// Pack W into MFMA-fragment-major bf16:
//   WbF[((n_blk*16 + kf)*64 + lane)*8 + j] =
//       bf16( W[n_blk*16 + (lane&15)][kf*32 + (lane>>4)*8 + j] )
__global__ void cvt_w_frag(const float* __restrict__ W,
                           unsigned short* __restrict__ WbF) {
    const int i    = blockIdx.x * 256 + threadIdx.x;  // 0..32767 fragments
    const int lane = i & 63;
    const int kf   = (i >> 6) & 15;
    const int nblk = i >> 10;                         // 0..31
    const int row  = nblk * 16 + (lane & 15);         // f index
    const int col  = kf * 32 + (lane >> 4) * 8;       // e index
    const float* p = W + (size_t)row * KD + col;
    float4 w0 = *reinterpret_cast<const float4*>(p);
    float4 w1 = *reinterpret_cast<const float4*>(p + 4);
    short8 t8;
    t8[0] = (short)f2bf(w0.x); t8[1] = (short)f2bf(w0.y);
    t8[2] = (short)f2bf(w0.z); t8[3] = (short)f2bf(w0.w);
    t8[4] = (short)f2bf(w1.x); t8[5] = (short)f2bf(w1.y);
    t8[6] = (short)f2bf(w1.z); t8[7] = (short)f2bf(w1.w);
    *reinterpret_cast<short8*>(WbF + (size_t)i * 8) = t8;
}

template <bool PRECVT>
__global__ __launch_bounds__(512, 2)
void fused_qgemm(const float* __restrict__ x, const float* __restrict__ theta,
                 const float* __restrict__ W, const unsigned short* __restrict__ WbF,
                 float* __restrict__ out) {
    __shared__ unsigned short A2[2][BM * KD];    // 2 x 32 KB bf16, swizzled
    __shared__ float          F[BM * KD];        // 64 KB fp32 staging, linear

    const int tid  = threadIdx.x;
    const int lane = tid & 63;
    const int wave = tid >> 6;                   // 0..7
    const int mb   = blockIdx.x * MPB;

    const int frow = lane & 15;
    const int fkg  = lane >> 4;

    constexpr float INV2PI = 0.15915493667125702f;
    float thC[8];
#pragma unroll
    for (int j = 0; j < 8; ++j) thC[j] = theta[j] * INV2PI;

    // ---- glds map: round r, thread t -> x[mb+s*32 + r*4 + (t>>7)][(t&127)*4..+3]
    //      F float-off = r*2048 + t*4  == wave-uniform (r*2048 + wave*256) + lane*4
    const int grow = tid >> 7;
    const int gcol = (tid & 127) * 4;
    const float* xbase = x + (size_t)(mb + grow) * KD + gcol;

    auto issueX = [&](int s) {
#pragma unroll
        for (int r = 0; r < 8; ++r) {
            const float* gp = xbase + (size_t)(s * BM + r * 4) * KD;
            __builtin_amdgcn_global_load_lds(
                (const __attribute__((address_space(1))) void*)gp,
                (__attribute__((address_space(3))) void*)&F[r * 2048 + wave * 256],
                16, 0, 0);
        }
    };

    // pack round r: thread t converts the 4 floats it loaded in round r
    const int tbase = (tid & 1) * 4;             // theta base = gcol & 7
    auto packX = [&](int r, unsigned short* Tb) {
        float4 v = *reinterpret_cast<const float4*>(&F[r * 2048 + tid * 4]);
        const int row = r * 4 + grow;
        float c0 = fast_cos_rev(__builtin_fmaf(v.x, INV2PI, thC[tbase + 0]));
        float c1 = fast_cos_rev(__builtin_fmaf(v.y, INV2PI, thC[tbase + 1]));
        float c2 = fast_cos_rev(__builtin_fmaf(v.z, INV2PI, thC[tbase + 2]));
        float c3 = fast_cos_rev(__builtin_fmaf(v.w, INV2PI, thC[tbase + 3]));
        unsigned int p01, p23;
        asm("v_cvt_pk_bf16_f32 %0, %1, %2" : "=v"(p01) : "v"(c0), "v"(c1));
        asm("v_cvt_pk_bf16_f32 %0, %1, %2" : "=v"(p23) : "v"(c2), "v"(c3));
        const int byte = row * 1024 + ((gcol * 2) ^ ((row & 7) << 4));
        uint2 pk; pk.x = p01; pk.y = p23;
        *reinterpret_cast<uint2*>(reinterpret_cast<char*>(Tb) + byte) = pk;
    };

    // ---- B: fragment-major base (fully coalesced 16B/lane loads) ----
    const unsigned short* wbase =
        PRECVT ? (WbF + ((size_t)wave * 4096 + lane) * 8) : nullptr;
    const float* wpf[4];
#pragma unroll
    for (int jn = 0; jn < 4; ++jn)
        wpf[jn] = W + (size_t)(wave * 64 + jn * 16 + frow) * KD + fkg * 8;

    auto loadB = [&](int kf, short8* dst) {
#pragma unroll
        for (int jn = 0; jn < 4; ++jn) {
            if (PRECVT) {
                dst[jn] = *reinterpret_cast<const short8*>(
                    wbase + (size_t)(jn * 16 + kf) * 512);
            } else {
                float4 w0 = *reinterpret_cast<const float4*>(wpf[jn] + kf * 32);
                float4 w1 = *reinterpret_cast<const float4*>(wpf[jn] + kf * 32 + 4);
                short8 t8;
                t8[0] = (short)f2bf(w0.x); t8[1] = (short)f2bf(w0.y);
                t8[2] = (short)f2bf(w0.z); t8[3] = (short)f2bf(w0.w);
                t8[4] = (short)f2bf(w1.x); t8[5] = (short)f2bf(w1.y);
                t8[6] = (short)f2bf(w1.z); t8[7] = (short)f2bf(w1.w);
                dst[jn] = t8;
            }
        }
    };

    auto loadA = [&](const unsigned short* buf, int kf, short8* dst) {
#pragma unroll
        for (int i = 0; i < 2; ++i) {
            const int row  = i * 16 + frow;
            const int byte = row * 1024 + (((kf * 32 + fkg * 8) * 2) ^ ((row & 7) << 4));
            dst[i] = *reinterpret_cast<const short8*>(
                reinterpret_cast<const char*>(buf) + byte);
        }
    };

    short8 bb[3][4];
    short8 aa[2][2];
    f32x4  acc[2][4];
#pragma unroll
    for (int i = 0; i < 2; ++i)
#pragma unroll
        for (int j = 0; j < 4; ++j) acc[i][j] = (f32x4)(0.0f);

    // ---- prologue: glds stripe 0 -> barrier (vmcnt0) -> pack A2[0] ----
    issueX(0);
    __syncthreads();
#pragma unroll
    for (int r = 0; r < 8; ++r) packX(r, (unsigned short*)A2[0]);
    __syncthreads();

    for (int s = 0; s < NST; ++s) {
        const unsigned short* curA = A2[s & 1];
        unsigned short*       nxtA = (unsigned short*)A2[(s & 1) ^ 1];
        const bool more = (s + 1 < NST);

        loadB(0, bb[0]);
        loadB(1, bb[1]);
        loadA(curA, 0, aa[0]);
#pragma unroll
        for (int kf = 0; kf < NKF; ++kf) {
            if (kf == 0 && more) issueX(s + 1);            // zero-reg async stage
            if (kf + 1 < NKF) loadA(curA, kf + 1, aa[(kf + 1) & 1]);
            if (kf + 2 < NKF) loadB(kf + 2, bb[(kf + 2) % 3]);
            __builtin_amdgcn_sched_barrier(0);
#pragma unroll
            for (int i = 0; i < 2; ++i)
#pragma unroll
                for (int jn = 0; jn < 4; ++jn)
                    acc[i][jn] = __builtin_amdgcn_mfma_f32_16x16x32_bf16(
                        bb[kf % 3][jn], aa[kf & 1][i], acc[i][jn], 0, 0, 0);
        }

        // ---- store stripe s (fire-and-forget; drains under next K-loop) ----
        float* op = out + (size_t)(mb + s * BM + frow) * ND + wave * 64 + fkg * 4;
#pragma unroll
        for (int i = 0; i < 2; ++i)
#pragma unroll
            for (int jn = 0; jn < 4; ++jn) {
                *reinterpret_cast<f32x4*>(op + (size_t)(i * 16) * ND + jn * 16) =
                    acc[i][jn];
                acc[i][jn] = (f32x4)(0.0f);
            }

        if (more) {
            __syncthreads();                   // drains glds (vmcnt0) + A2 reads
#pragma unroll
            for (int r = 0; r < 8; ++r) packX(r, nxtA);
            __syncthreads();                   // A2[next] visible to all waves
        }
    }
}

extern "C" void kernel_launch(void* const* d_in, const int* in_sizes, int n_in,
                              void* d_out, int out_size, void* d_ws, size_t ws_size,
                              hipStream_t stream) {
    const float* x     = (const float*)d_in[0];
    const float* theta = (const float*)d_in[1];
    const float* W     = (const float*)d_in[2];
    float* out         = (float*)d_out;

    const int M      = in_sizes[0] / KD;       // 65536
    const int wElems = in_sizes[2];            // 512*512

    if (ws_size >= (size_t)wElems * sizeof(unsigned short)) {
        unsigned short* WbF = (unsigned short*)d_ws;
        cvt_w_frag<<<wElems / 8 / 256, 256, 0, stream>>>(W, WbF);
        fused_qgemm<true><<<M / MPB, 512, 0, stream>>>(x, theta, W, WbF, out);
    } else {
        fused_qgemm<false><<<M / MPB, 512, 0, stream>>>(x, theta, W, nullptr, out);
    }
}

// Round 12
// 82.747 us; speedup vs baseline: 2.3992x; 2.3552x over previous
//
#include <hip/hip_runtime.h>
#include <hip/hip_bf16.h>

// out[m, f] = sum_e cos(x[m, e] + theta[e & 7]) * W[f, e]
// M = 65536, N = K = 512.  bf16 MFMA GEMM, A = cos(x+theta) fused.
//
// R5 structure (proven spill-free) + K-SLICED STAGING:
// block = 32x512 stripe, ONE 32 KB LDS tile, 8 phases.  Phase p:
//   1. load x-slice p+1: ONE float4/thread (4 VGPRs in flight)
//   2. kf = 2p, 2p+1: ds_read A-slice p + fragment-major B (1-ahead) + 16 MFMA
//   3. pack slice p+1: fract+v_cos+v_cvt_pk_bf16 -> 8B ds_write
//   4. __syncthreads()  (implicit vmcnt(0) = the only wait; no inline asm)
// Slices are disjoint columns -> no double buffer.  x/B/out/MFMA overlap
// continuously; stores drain under the next block (2 blocks/CU resident).
// Registers: acc 32(AGPR) + bb 32 + aa 16 + xv 4 + misc ~= 112 < 128 cap.

typedef __attribute__((ext_vector_type(8))) short short8;   // 8 x bf16
typedef __attribute__((ext_vector_type(4))) float f32x4;    // MFMA acc frag

static constexpr int KD  = 512;
static constexpr int ND  = 512;
static constexpr int BM  = 32;
static constexpr int NKF = 16;           // K steps of 32
static constexpr int NPH = 8;            // phases (2 kf each)

static __device__ __forceinline__ unsigned short f2bf(float f) {
    unsigned int b = __builtin_bit_cast(unsigned int, f);
    b += 0x7FFFu + ((b >> 16) & 1u);
    return (unsigned short)(b >> 16);
}

// cos(2*pi*rev) via v_cos_f32 (input in revolutions, fract range-reduce)
static __device__ __forceinline__ float fast_cos_rev(float rev) {
    float r = __builtin_amdgcn_fractf(rev);
    float c;
    asm("v_cos_f32 %0, %1" : "=v"(c) : "v"(r));
    return c;
}

// Pack W into MFMA-fragment-major bf16:
//   WbF[((n_blk*16 + kf)*64 + lane)*8 + j] =
//       bf16( W[n_blk*16 + (lane&15)][kf*32 + (lane>>4)*8 + j] )
__global__ void cvt_w_frag(const float* __restrict__ W,
                           unsigned short* __restrict__ WbF) {
    const int i    = blockIdx.x * 256 + threadIdx.x;  // 0..32767 fragments
    const int lane = i & 63;
    const int kf   = (i >> 6) & 15;
    const int nblk = i >> 10;                         // 0..31
    const int row  = nblk * 16 + (lane & 15);         // f index
    const int col  = kf * 32 + (lane >> 4) * 8;       // e index
    const float* p = W + (size_t)row * KD + col;
    float4 w0 = *reinterpret_cast<const float4*>(p);
    float4 w1 = *reinterpret_cast<const float4*>(p + 4);
    short8 t8;
    t8[0] = (short)f2bf(w0.x); t8[1] = (short)f2bf(w0.y);
    t8[2] = (short)f2bf(w0.z); t8[3] = (short)f2bf(w0.w);
    t8[4] = (short)f2bf(w1.x); t8[5] = (short)f2bf(w1.y);
    t8[6] = (short)f2bf(w1.z); t8[7] = (short)f2bf(w1.w);
    *reinterpret_cast<short8*>(WbF + (size_t)i * 8) = t8;
}

template <bool PRECVT>
__global__ __launch_bounds__(512, 4)
void fused_qgemm(const float* __restrict__ x, const float* __restrict__ theta,
                 const float* __restrict__ W, const unsigned short* __restrict__ WbF,
                 float* __restrict__ out) {
    __shared__ unsigned short A[BM * KD];   // 32 KB, pitch 1024 B, XOR-swizzled

    const int tid  = threadIdx.x;
    const int lane = tid & 63;
    const int wave = tid >> 6;              // 0..7 -> n0 = wave*64
    const int m0   = blockIdx.x * BM;

    const int frow = lane & 15;
    const int fkg  = lane >> 4;

    constexpr float INV2PI = 0.15915493667125702f;
    float thC[8];
#pragma unroll
    for (int j = 0; j < 8; ++j) thC[j] = theta[j] * INV2PI;

    // ---- slice staging map: thread t -> row t>>4, 4 cols at (t&15)*4 ----
    const int prow = tid >> 4;              // 0..31
    const int pc4  = (tid & 15) * 4;        // 0..60
    const int tb   = (tid & 1) * 4;         // theta base = col & 7
    const int pswz = (prow & 7) << 4;
    const float* xp = x + (size_t)(m0 + prow) * KD + pc4;

    auto loadX = [&](int p) -> float4 {
        return *reinterpret_cast<const float4*>(xp + p * 64);
    };
    auto packX = [&](int p, float4 v) {
        float c0 = fast_cos_rev(__builtin_fmaf(v.x, INV2PI, thC[tb + 0]));
        float c1 = fast_cos_rev(__builtin_fmaf(v.y, INV2PI, thC[tb + 1]));
        float c2 = fast_cos_rev(__builtin_fmaf(v.z, INV2PI, thC[tb + 2]));
        float c3 = fast_cos_rev(__builtin_fmaf(v.w, INV2PI, thC[tb + 3]));
        unsigned int p01, p23;
        asm("v_cvt_pk_bf16_f32 %0, %1, %2" : "=v"(p01) : "v"(c0), "v"(c1));
        asm("v_cvt_pk_bf16_f32 %0, %1, %2" : "=v"(p23) : "v"(c2), "v"(c3));
        const int col  = p * 64 + pc4;
        const int byte = prow * 1024 + ((col * 2) ^ pswz);
        uint2 pk; pk.x = p01; pk.y = p23;
        *reinterpret_cast<uint2*>(reinterpret_cast<char*>(A) + byte) = pk;
    };

    // ---- B: fragment-major base (fully coalesced 16B/lane loads) ----
    const unsigned short* wbase =
        PRECVT ? (WbF + ((size_t)wave * 4096 + lane) * 8) : nullptr;
    const float* wpf[4];
#pragma unroll
    for (int jn = 0; jn < 4; ++jn)
        wpf[jn] = W + (size_t)(wave * 64 + jn * 16 + frow) * KD + fkg * 8;

    auto loadB = [&](int kf, short8* dst) {
#pragma unroll
        for (int jn = 0; jn < 4; ++jn) {
            if (PRECVT) {
                dst[jn] = *reinterpret_cast<const short8*>(
                    wbase + (size_t)(jn * 16 + kf) * 512);
            } else {
                float4 w0 = *reinterpret_cast<const float4*>(wpf[jn] + kf * 32);
                float4 w1 = *reinterpret_cast<const float4*>(wpf[jn] + kf * 32 + 4);
                short8 t8;
                t8[0] = (short)f2bf(w0.x); t8[1] = (short)f2bf(w0.y);
                t8[2] = (short)f2bf(w0.z); t8[3] = (short)f2bf(w0.w);
                t8[4] = (short)f2bf(w1.x); t8[5] = (short)f2bf(w1.y);
                t8[6] = (short)f2bf(w1.z); t8[7] = (short)f2bf(w1.w);
                dst[jn] = t8;
            }
        }
    };

    auto loadA = [&](int kf, short8* dst) {
#pragma unroll
        for (int i = 0; i < 2; ++i) {
            const int row  = i * 16 + frow;
            const int byte = row * 1024 + (((kf * 32 + fkg * 8) * 2) ^ ((row & 7) << 4));
            dst[i] = *reinterpret_cast<const short8*>(
                reinterpret_cast<const char*>(A) + byte);
        }
    };

    short8 bb[2][4];
    short8 aa[2][2];
    f32x4  acc[2][4];
#pragma unroll
    for (int i = 0; i < 2; ++i)
#pragma unroll
        for (int j = 0; j < 4; ++j) acc[i][j] = (f32x4)(0.0f);

    // ---- prologue: slice 0 + B(0) ----
    {
        float4 xv = loadX(0);
        loadB(0, bb[0]);
        packX(0, xv);
    }
    __syncthreads();

    // ---- 8 phases, 2 kf each ----
#pragma unroll
    for (int p = 0; p < NPH; ++p) {
        const int k0 = 2 * p;
        float4 xv;
        if (p + 1 < NPH) xv = loadX(p + 1);       // 1 float4 in flight

        loadA(k0, aa[0]);
        if (k0 + 1 < NKF) loadB(k0 + 1, bb[1]);
        loadA(k0 + 1, aa[1]);

#pragma unroll
        for (int i = 0; i < 2; ++i)               // kf = k0 (bb[0], aa[0])
#pragma unroll
            for (int jn = 0; jn < 4; ++jn)
                acc[i][jn] = __builtin_amdgcn_mfma_f32_16x16x32_bf16(
                    bb[0][jn], aa[0][i], acc[i][jn], 0, 0, 0);

        if (k0 + 2 < NKF) loadB(k0 + 2, bb[0]);   // next phase's first B

#pragma unroll
        for (int i = 0; i < 2; ++i)               // kf = k0+1 (bb[1], aa[1])
#pragma unroll
            for (int jn = 0; jn < 4; ++jn)
                acc[i][jn] = __builtin_amdgcn_mfma_f32_16x16x32_bf16(
                    bb[1][jn], aa[1][i], acc[i][jn], 0, 0, 0);

        if (p + 1 < NPH) {
            packX(p + 1, xv);                     // writes slice p+1 cols only
            __syncthreads();                      // vmcnt(0)+lgkmcnt(0) drain
        }
    }

    // ---- epilogue: m = m0 + i*16 + frow, n = wave*64 + jn*16 + fkg*4 + r ----
    float* op = out + (size_t)(m0 + frow) * ND + wave * 64 + fkg * 4;
#pragma unroll
    for (int i = 0; i < 2; ++i)
#pragma unroll
        for (int jn = 0; jn < 4; ++jn)
            *reinterpret_cast<f32x4*>(op + (size_t)(i * 16) * ND + jn * 16) =
                acc[i][jn];
}

extern "C" void kernel_launch(void* const* d_in, const int* in_sizes, int n_in,
                              void* d_out, int out_size, void* d_ws, size_t ws_size,
                              hipStream_t stream) {
    const float* x     = (const float*)d_in[0];
    const float* theta = (const float*)d_in[1];
    const float* W     = (const float*)d_in[2];
    float* out         = (float*)d_out;

    const int M      = in_sizes[0] / KD;       // 65536
    const int wElems = in_sizes[2];            // 512*512

    if (ws_size >= (size_t)wElems * sizeof(unsigned short)) {
        unsigned short* WbF = (unsigned short*)d_ws;
        cvt_w_frag<<<wElems / 8 / 256, 256, 0, stream>>>(W, WbF);
        fused_qgemm<true><<<M / BM, 512, 0, stream>>>(x, theta, W, WbF, out);
    } else {
        fused_qgemm<false><<<M / BM, 512, 0, stream>>>(x, theta, W, nullptr, out);
    }
}